// Round 6
// baseline (322.838 us; speedup 1.0000x reference)
//
#include <hip/hip_runtime.h>
#include <hip/hip_bf16.h>
#include <stdint.h>

typedef __attribute__((ext_vector_type(8))) __bf16 bf8v;   // MFMA A/B frag: 8 bf16 = 4 VGPR
typedef __attribute__((ext_vector_type(4))) float f4v;     // MFMA C/D frag

#define L2E 1.44269504088896f

// fp32 -> bf16 round-to-nearest-even (bit pattern as ushort)
__device__ __forceinline__ unsigned short f2bf(float f) {
  union { float f; unsigned u; } v; v.f = f;
  unsigned r = v.u + 0x7fffu + ((v.u >> 16) & 1u);
  return (unsigned short)(r >> 16);
}

// pack two fp32 -> dword of two RNE bf16 (low = f0), HW v_cvt_pk_bf16_f32 path
__device__ __forceinline__ unsigned pk2bf(float f0, float f1) {
  union { __hip_bfloat162 h; unsigned u; } c;
  c.h = __float22bfloat162_rn(make_float2(f0, f1));
  return c.u;
}

// 2^x via v_exp_f32
__device__ __forceinline__ float exp2_hw(float x) {
  return __builtin_amdgcn_exp2f(x);
}

// async global->LDS, 16B per lane; LDS dest = wave-uniform base + lane*16
__device__ __forceinline__ void gl_lds16(const void* g, void* l) {
  __builtin_amdgcn_global_load_lds(
      (__attribute__((address_space(1))) void*)(g),
      (__attribute__((address_space(3))) void*)(l), 16, 0, 0);
}

__device__ __forceinline__ void store_out(unsigned short* p, float v) { *p = f2bf(v); }
__device__ __forceinline__ void store_out(float* p, float v) { *p = v; }

// ---------------- fused prep: cast x -> bf16  +  weight transpose/cast ----------------
__global__ void prep_kernel(const float* __restrict__ x,
                            const float* __restrict__ w_in,
                            const float* __restrict__ w_out,
                            unsigned short* __restrict__ xb,
                            unsigned short* __restrict__ wiT,
                            unsigned short* __restrict__ woT) {
  __shared__ float tile[32][33];
  int bx = blockIdx.x;
  if (bx < 8192) {
    int i = bx * 256 + threadIdx.x;
    float4 v = ((const float4*)x)[i];
    ushort4 o;
    o.x = f2bf(v.x); o.y = f2bf(v.y); o.z = f2bf(v.z); o.w = f2bf(v.w);
    ((ushort4*)xb)[i] = o;
    return;
  }
  int idx = bx - 8192;              // 0..4095 -> (128 x, 32 y)
  int bxx = idx & 127, byy = idx >> 7;
  const float* in; unsigned short* out; int C, c0;
  if (bxx < 96) { in = w_in;  out = wiT; C = 3072; c0 = bxx * 32; }
  else          { in = w_out; out = woT; C = 1024; c0 = (bxx - 96) * 32; }
  int r0 = byy * 32;
  int tx = threadIdx.x & 31, ty = threadIdx.x >> 5;
#pragma unroll
  for (int j = 0; j < 4; ++j)
    tile[ty + 8 * j][tx] = in[(size_t)(r0 + ty + 8 * j) * C + c0 + tx];
  __syncthreads();
#pragma unroll
  for (int j = 0; j < 4; ++j)
    out[(size_t)(c0 + ty + 8 * j) * 1024 + r0 + tx] = f2bf(tile[tx][ty + 8 * j]);
}

// ---------------- V transpose: qkv v-part -> vtg[b][h][d][n] (bf16) ----------------
__global__ void transpose_v_kernel(const unsigned short* __restrict__ qkv,
                                   unsigned short* __restrict__ vtg) {
  __shared__ unsigned short tile[32][33];
  int bh = blockIdx.z;            // b*16 + h
  int d0 = blockIdx.y * 32;       // 0 or 32
  int n0 = blockIdx.x * 32;
  int b = bh >> 4, h = bh & 15;
  int tx = threadIdx.x, ty = threadIdx.y;
  const unsigned short* src = qkv + (size_t)b * 2048 * 3072 + 2048 + h * 64 + d0;
#pragma unroll
  for (int j = 0; j < 4; ++j)
    tile[ty + 8 * j][tx] = src[(size_t)(n0 + ty + 8 * j) * 3072 + tx];
  __syncthreads();
  unsigned short* dst = vtg + ((size_t)bh * 64) * 2048;
#pragma unroll
  for (int j = 0; j < 4; ++j)
    dst[(size_t)(d0 + ty + 8 * j) * 2048 + n0 + tx] = tile[tx][ty + 8 * j];
}

// ---------------- GEMM: 256x128 tile, BK=64, deep pipeline, templated output ----------------
// (unchanged from round 5 — delivered the predicted gain)
template <typename OutT, bool SCALE>
__global__ __launch_bounds__(512, 2) void gemm256(
    const unsigned short* __restrict__ A,
    const unsigned short* __restrict__ BT,
    const float* __restrict__ bias,
    OutT* __restrict__ C,
    int N, int K, int nbx, int scale_ncols, float scale) {
  __shared__ __align__(16) unsigned short As[2][256 * 64];
  __shared__ __align__(16) unsigned short Bs[2][128 * 64];
  const int tid = threadIdx.x;
  const int wave = tid >> 6, lane = tid & 63;
  const int lo = lane & 15, hi = lane >> 4;
  const int wm = wave >> 1, wn = wave & 1;

  const int cpx = gridDim.x >> 3;
  const int s = (blockIdx.x & 7) * cpx + (blockIdx.x >> 3);
  const int by = s / nbx, bx = s - by * nbx;
  const int m0 = by * 256, n0 = bx * 128;

  const int srow = lane >> 3;
  const int scol = (((lane & 7) ^ (srow & 7)) * 8);
  const unsigned short* gA = A + (size_t)(m0 + wave * 8 + srow) * K + scol;
  const unsigned short* gB = BT + (size_t)(n0 + wave * 8 + srow) * K + scol;

  const int csw0 = ((hi ^ (lo & 7)) * 8);
  const int csw1 = (((4 + hi) ^ (lo & 7)) * 8);
  const int rA = wm * 64;   // + i*16 + lo
  const int rB = wn * 64;   // + j*16 + lo

  f4v acc[4][4] = {};
  const int nt = K >> 6;

#pragma unroll
  for (int j = 0; j < 4; ++j)
    gl_lds16(gA + (size_t)(j * 64) * K, &As[0][(j * 64 + wave * 8) * 64]);
#pragma unroll
  for (int j = 0; j < 2; ++j)
    gl_lds16(gB + (size_t)(j * 64) * K, &Bs[0][(j * 64 + wave * 8) * 64]);

  for (int t = 0; t < nt; ++t) {
    const int c = t & 1;
    __builtin_amdgcn_s_barrier();   // readers of parity c^1 (tile t-1) done
    __builtin_amdgcn_sched_barrier(0);
    if (t + 1 < nt) {
      const unsigned short* gA1 = gA + (size_t)(t + 1) * 64;
      const unsigned short* gB1 = gB + (size_t)(t + 1) * 64;
#pragma unroll
      for (int j = 0; j < 4; ++j)
        gl_lds16(gA1 + (size_t)(j * 64) * K, &As[c ^ 1][(j * 64 + wave * 8) * 64]);
#pragma unroll
      for (int j = 0; j < 2; ++j)
        gl_lds16(gB1 + (size_t)(j * 64) * K, &Bs[c ^ 1][(j * 64 + wave * 8) * 64]);
      asm volatile("s_waitcnt vmcnt(6)" ::: "memory");  // tile t landed; t+1 in flight
    } else {
      asm volatile("s_waitcnt vmcnt(0)" ::: "memory");
    }
    __builtin_amdgcn_sched_barrier(0);
    __builtin_amdgcn_s_barrier();   // all waves' tile-t data visible
    __builtin_amdgcn_sched_barrier(0);

    bf8v b[4][2];
#pragma unroll
    for (int fn = 0; fn < 4; ++fn) {
      b[fn][0] = *(const bf8v*)&Bs[c][(rB + fn * 16 + lo) * 64 + csw0];
      b[fn][1] = *(const bf8v*)&Bs[c][(rB + fn * 16 + lo) * 64 + csw1];
    }
#pragma unroll
    for (int p = 0; p < 2; ++p) {
      bf8v a[2][2];
#pragma unroll
      for (int i = 0; i < 2; ++i) {
        a[i][0] = *(const bf8v*)&As[c][(rA + (p * 2 + i) * 16 + lo) * 64 + csw0];
        a[i][1] = *(const bf8v*)&As[c][(rA + (p * 2 + i) * 16 + lo) * 64 + csw1];
      }
      __builtin_amdgcn_s_setprio(1);
#pragma unroll
      for (int ks = 0; ks < 2; ++ks)
#pragma unroll
        for (int i = 0; i < 2; ++i)
#pragma unroll
          for (int fn = 0; fn < 4; ++fn)
            acc[p * 2 + i][fn] = __builtin_amdgcn_mfma_f32_16x16x32_bf16(
                a[i][ks], b[fn][ks], acc[p * 2 + i][fn], 0, 0, 0);
      __builtin_amdgcn_s_setprio(0);
    }
  }

#pragma unroll
  for (int i = 0; i < 4; ++i) {
#pragma unroll
    for (int r = 0; r < 4; ++r) {
      int row = m0 + wm * 64 + i * 16 + hi * 4 + r;
#pragma unroll
      for (int j = 0; j < 4; ++j) {
        int col = n0 + wn * 64 + j * 16 + lo;
        float v = acc[i][j][r] + bias[col];
        if (SCALE && col < scale_ncols) v *= scale;
        store_out(&C[(size_t)row * N + col], v);
      }
    }
  }
}

// ---------------- flash attention v8: BARRIER-FREE ----------------
// v5/v6/v7 all plateau at ~93us with MfmaUtil 35 / VALU 40 / nothing saturated:
// the per-kt barrier phase-locks all waves into the same phase (all QK^T, then
// all softmax, then all PV) so the MFMA and VALU pipes alternate saturated/idle.
// Fix: K/V are L2-resident (FETCH=24.6MB proves it) -> load K/V MFMA fragments
// DIRECTLY from global to registers (same row/col gather as the LDS frag reads).
// LDS keeps only the wave-PRIVATE P tile -> zero barriers; waves drift into
// complementary phases and the pipes overlap across waves. setprio arbitrates.
#define FSTR 72   // LDS row stride (shorts): 64 payload + 8 pad

__global__ __launch_bounds__(256, 2) void flash_attn(
    const unsigned short* __restrict__ qkv,
    const unsigned short* __restrict__ vtg,
    unsigned short* __restrict__ y) {
  __shared__ __align__(16) unsigned short Ps[256 * FSTR];  // P tile [q][key], wave-private rows
  const int tid = threadIdx.x;
  const int wave = tid >> 6, lane = tid & 63;
  const int lo = lane & 15, hi = lane >> 4;

  // XCD swizzle: 512 blocks; XCD c gets one b, 8 heads (~4MB KV -> L2-resident)
  const int lin = blockIdx.x;
  const int swz = (lin & 7) * 64 + (lin >> 3);
  const int q0 = (swz & 7) << 8;        // 8 q-blocks of 256
  const int h  = (swz >> 3) & 15;
  const int b  = swz >> 7;

  const size_t base = (size_t)b * 2048 * 3072;
  const int qoff = h * 64, koff = 1024 + h * 64;
  const unsigned short* vsrc = vtg + (size_t)(b * 16 + h) * 64 * 2048;
  const unsigned short* kg = qkv + base + koff;

  // Q^T B-operand frags, loaded DIRECTLY from global (B[k][col]: col=lo -> q-row,
  // k=hi*8.. -> d). Q columns were pre-scaled by log2e in gemm1.
  bf8v bq[4][2];  // [qt][ks]
#pragma unroll
  for (int qt = 0; qt < 4; ++qt)
#pragma unroll
    for (int ks = 0; ks < 2; ++ks)
      bq[qt][ks] = *(const bf8v*)(qkv + base +
          (size_t)(q0 + wave * 64 + qt * 16 + lo) * 3072 + qoff + ks * 32 + hi * 8);

  f4v O[4][4] = {};       // [qt][dt]
  f4v acc_l[4] = {};      // row-sums via MFMA x ones (same C/D layout as O)
  union { bf8v v; unsigned short u[8]; } onesu;
#pragma unroll
  for (int i = 0; i < 8; ++i) onesu.u[i] = 0x3F80;  // bf16 1.0
  const bf8v ones = onesu.v;

  const int prow = (wave * 64 + lo) * FSTR;  // base of this lane's P rows (+qt*16*FSTR)

  for (int kt = 0; kt < 32; ++kt) {
    const unsigned short* kb = kg + (size_t)kt * 64 * 3072;
    const unsigned short* vb = vsrc + kt * 64;

    // K fragments (A-operand: row=key=ct*16+lo, col=d=ks*32+hi*8) — global direct.
    bf8v kn[4][2];
#pragma unroll
    for (int ct = 0; ct < 4; ++ct)
#pragma unroll
      for (int ks = 0; ks < 2; ++ks)
        kn[ct][ks] = *(const bf8v*)(kb + (size_t)(ct * 16 + lo) * 3072 + ks * 32 + hi * 8);
    // V^T fragments (B-operand for PV: row=d=dt*16+lo, col=key=ks*32+hi*8) — issued
    // now so they're in flight under QK^T; compiler places the counted vmcnt waits.
    bf8v vn[4][2];
#pragma unroll
    for (int dt = 0; dt < 4; ++dt)
#pragma unroll
      for (int ks = 0; ks < 2; ++ks)
        vn[dt][ks] = *(const bf8v*)(vb + (size_t)(dt * 16 + lo) * 2048 + ks * 32 + hi * 8);

    // ---- S^T = K . Q~^T per 16-key strip; softmax strip as it finishes
#pragma unroll
    for (int ct = 0; ct < 4; ++ct) {
      f4v s[4] = {{}, {}, {}, {}};
      __builtin_amdgcn_s_setprio(1);
#pragma unroll
      for (int ks = 0; ks < 2; ++ks)
#pragma unroll
        for (int qt = 0; qt < 4; ++qt)
          s[qt] = __builtin_amdgcn_mfma_f32_16x16x32_bf16(kn[ct][ks], bq[qt][ks], s[qt], 0, 0, 0);
      __builtin_amdgcn_s_setprio(0);
#pragma unroll
      for (int qt = 0; qt < 4; ++qt) {
        float p0 = exp2_hw(s[qt][0]), p1 = exp2_hw(s[qt][1]);
        float p2 = exp2_hw(s[qt][2]), p3 = exp2_hw(s[qt][3]);
        uint2 w; w.x = pk2bf(p0, p1); w.y = pk2bf(p2, p3);
        *(uint2*)&Ps[prow + qt * 16 * FSTR + ct * 16 + hi * 4] = w;
      }
    }

    // ---- O += P.V ; l += P.1  (P round-trip is in-wave: lgkm ordering only)
#pragma unroll
    for (int ks = 0; ks < 2; ++ks) {
      bf8v ap[4];
#pragma unroll
      for (int qt = 0; qt < 4; ++qt)
        ap[qt] = *(const bf8v*)&Ps[prow + qt * 16 * FSTR + ks * 32 + hi * 8];
      __builtin_amdgcn_s_setprio(1);
#pragma unroll
      for (int qt = 0; qt < 4; ++qt)
        acc_l[qt] = __builtin_amdgcn_mfma_f32_16x16x32_bf16(ap[qt], ones, acc_l[qt], 0, 0, 0);
#pragma unroll
      for (int dt = 0; dt < 4; ++dt)
#pragma unroll
        for (int qt = 0; qt < 4; ++qt)
          O[qt][dt] = __builtin_amdgcn_mfma_f32_16x16x32_bf16(ap[qt], vn[dt][ks], O[qt][dt], 0, 0, 0);
      __builtin_amdgcn_s_setprio(0);
    }
  }

  // epilogue: acc_l matches O's C/D layout -> no cross-lane reduction
#pragma unroll
  for (int qt = 0; qt < 4; ++qt) {
#pragma unroll
    for (int r = 0; r < 4; ++r) {
      float inv = 1.f / acc_l[qt][r];
      int row = q0 + wave * 64 + qt * 16 + hi * 4 + r;
      size_t orow = ((size_t)b * 2048 + row) * 1024 + h * 64;
#pragma unroll
      for (int dt = 0; dt < 4; ++dt)
        y[orow + dt * 16 + lo] = f2bf(O[qt][dt][r] * inv);
    }
  }
}

// ---------------- launch ----------------
extern "C" void kernel_launch(void* const* d_in, const int* in_sizes, int n_in,
                              void* d_out, int out_size, void* d_ws, size_t ws_size,
                              hipStream_t stream) {
  (void)in_sizes; (void)n_in; (void)out_size; (void)ws_size;
  const float* x     = (const float*)d_in[0];
  const float* w_in  = (const float*)d_in[1];
  const float* b_in  = (const float*)d_in[2];
  const float* w_out = (const float*)d_in[3];
  const float* b_out = (const float*)d_in[4];

  // workspace layout (bf16 elements): vtg aliases xb (xb dead after gemm1)
  unsigned short* xb  = (unsigned short*)d_ws;          // 8192x1024 (later: vtg 64x64x2048)
  unsigned short* wiT = xb  + (size_t)8192 * 1024;      // 3072x1024 (w_in^T)
  unsigned short* woT = wiT + (size_t)3072 * 1024;      // 1024x1024 (w_out^T)
  unsigned short* qkv = woT + (size_t)1024 * 1024;      // 8192x3072
  unsigned short* yb  = qkv + (size_t)8192 * 3072;      // 8192x1024
  unsigned short* vtg = xb;                             // alias: 64*64*2048 == 8192*1024

  // cast + weight transpose fused (one launch)
  prep_kernel<<<12288, 256, 0, stream>>>(x, w_in, w_out, xb, wiT, woT);

  // qkv = x @ w_in + b_in; Q columns (<1024) scaled by log2(e) for exp2 softmax
  gemm256<unsigned short, true><<<768, 512, 0, stream>>>(
      xb, wiT, b_in, qkv, 3072, 1024, 24, 1024, L2E);
  // vtg[b][h][d][n] = V^T  (xb is dead now; reuse its space)
  transpose_v_kernel<<<dim3(64, 2, 64), dim3(32, 8), 0, stream>>>(qkv, vtg);
  // attention -> yb
  flash_attn<<<512, 256, 0, stream>>>(qkv, vtg, yb);
  // out = yb @ w_out + b_out; 256x128 tiles: grid 32x8 = 256 blocks = 1 round
  gemm256<float, false><<<256, 512, 0, stream>>>(
      yb, woT, b_out, (float*)d_out, 1024, 1024, 8, 0, 1.0f);
}

// Round 7
// 274.816 us; speedup vs baseline: 1.1747x; 1.1747x over previous
//
#include <hip/hip_runtime.h>
#include <hip/hip_bf16.h>
#include <stdint.h>

typedef __attribute__((ext_vector_type(8))) __bf16 bf8v;   // MFMA A/B frag: 8 bf16 = 4 VGPR
typedef __attribute__((ext_vector_type(4))) float f4v;     // MFMA C/D frag

#define L2E 1.44269504088896f

// fp32 -> bf16 round-to-nearest-even (bit pattern as ushort)
__device__ __forceinline__ unsigned short f2bf(float f) {
  union { float f; unsigned u; } v; v.f = f;
  unsigned r = v.u + 0x7fffu + ((v.u >> 16) & 1u);
  return (unsigned short)(r >> 16);
}

// pack two fp32 -> dword of two RNE bf16 (low = f0), HW v_cvt_pk_bf16_f32 path
__device__ __forceinline__ unsigned pk2bf(float f0, float f1) {
  union { __hip_bfloat162 h; unsigned u; } c;
  c.h = __float22bfloat162_rn(make_float2(f0, f1));
  return c.u;
}

// 2^x via v_exp_f32
__device__ __forceinline__ float exp2_hw(float x) {
  return __builtin_amdgcn_exp2f(x);
}

// async global->LDS, 16B per lane; LDS dest = wave-uniform base + lane*16
__device__ __forceinline__ void gl_lds16(const void* g, void* l) {
  __builtin_amdgcn_global_load_lds(
      (__attribute__((address_space(1))) void*)(g),
      (__attribute__((address_space(3))) void*)(l), 16, 0, 0);
}

// ---------------- fused prep: cast x -> bf16  +  weight transpose/cast ----------------
__global__ void prep_kernel(const float* __restrict__ x,
                            const float* __restrict__ w_in,
                            const float* __restrict__ w_out,
                            unsigned short* __restrict__ xb,
                            unsigned short* __restrict__ wiT,
                            unsigned short* __restrict__ woT) {
  __shared__ float tile[32][33];
  int bx = blockIdx.x;
  if (bx < 8192) {
    int i = bx * 256 + threadIdx.x;
    float4 v = ((const float4*)x)[i];
    ushort4 o;
    o.x = f2bf(v.x); o.y = f2bf(v.y); o.z = f2bf(v.z); o.w = f2bf(v.w);
    ((ushort4*)xb)[i] = o;
    return;
  }
  int idx = bx - 8192;              // 0..4095 -> (128 x, 32 y)
  int bxx = idx & 127, byy = idx >> 7;
  const float* in; unsigned short* out; int C, c0;
  if (bxx < 96) { in = w_in;  out = wiT; C = 3072; c0 = bxx * 32; }
  else          { in = w_out; out = woT; C = 1024; c0 = (bxx - 96) * 32; }
  int r0 = byy * 32;
  int tx = threadIdx.x & 31, ty = threadIdx.x >> 5;
#pragma unroll
  for (int j = 0; j < 4; ++j)
    tile[ty + 8 * j][tx] = in[(size_t)(r0 + ty + 8 * j) * C + c0 + tx];
  __syncthreads();
#pragma unroll
  for (int j = 0; j < 4; ++j)
    out[(size_t)(c0 + ty + 8 * j) * 1024 + r0 + tx] = f2bf(tile[tx][ty + 8 * j]);
}

// ---------------- GEMM: 256x128 tile, BK=64, deep pipeline ----------------
// MODE 1 (qkv): bf16 out. cols<1024 (Q) scaled by L2E -> C[row*2048+col];
//   cols in [1024,2048) (K) -> C[row*2048+col]; cols>=2048 (V) -> transposed
//   write vtg[b][h][d][token] (ushort4 = 4 consecutive tokens). The separate
//   transpose_v kernel is gone; qkv's V-columns are never materialized.
// MODE 0: fp32 out C[row*N+col] (gemm2).
// Inner loop identical to round-5 (verified): 2-barrier/K-tile, counted vmcnt(6),
// full 3-bit XOR swizzle both-sides, setprio around MFMA clusters.
template <int MODE>
__global__ __launch_bounds__(512, 2) void gemm256(
    const unsigned short* __restrict__ A,
    const unsigned short* __restrict__ BT,
    const float* __restrict__ bias,
    void* __restrict__ Cv,
    unsigned short* __restrict__ vtg,
    int N, int K, int nbx, float scale) {
  __shared__ __align__(16) unsigned short As[2][256 * 64];
  __shared__ __align__(16) unsigned short Bs[2][128 * 64];
  const int tid = threadIdx.x;
  const int wave = tid >> 6, lane = tid & 63;
  const int lo = lane & 15, hi = lane >> 4;
  const int wm = wave >> 1, wn = wave & 1;

  const int cpx = gridDim.x >> 3;
  const int s = (blockIdx.x & 7) * cpx + (blockIdx.x >> 3);
  const int by = s / nbx, bx = s - by * nbx;
  const int m0 = by * 256, n0 = bx * 128;

  const int srow = lane >> 3;
  const int scol = (((lane & 7) ^ (srow & 7)) * 8);
  const unsigned short* gA = A + (size_t)(m0 + wave * 8 + srow) * K + scol;
  const unsigned short* gB = BT + (size_t)(n0 + wave * 8 + srow) * K + scol;

  const int csw0 = ((hi ^ (lo & 7)) * 8);
  const int csw1 = (((4 + hi) ^ (lo & 7)) * 8);
  const int rA = wm * 64;   // + i*16 + lo
  const int rB = wn * 64;   // + j*16 + lo

  f4v acc[4][4] = {};
  const int nt = K >> 6;

#pragma unroll
  for (int j = 0; j < 4; ++j)
    gl_lds16(gA + (size_t)(j * 64) * K, &As[0][(j * 64 + wave * 8) * 64]);
#pragma unroll
  for (int j = 0; j < 2; ++j)
    gl_lds16(gB + (size_t)(j * 64) * K, &Bs[0][(j * 64 + wave * 8) * 64]);

  for (int t = 0; t < nt; ++t) {
    const int c = t & 1;
    __builtin_amdgcn_s_barrier();   // readers of parity c^1 (tile t-1) done
    __builtin_amdgcn_sched_barrier(0);
    if (t + 1 < nt) {
      const unsigned short* gA1 = gA + (size_t)(t + 1) * 64;
      const unsigned short* gB1 = gB + (size_t)(t + 1) * 64;
#pragma unroll
      for (int j = 0; j < 4; ++j)
        gl_lds16(gA1 + (size_t)(j * 64) * K, &As[c ^ 1][(j * 64 + wave * 8) * 64]);
#pragma unroll
      for (int j = 0; j < 2; ++j)
        gl_lds16(gB1 + (size_t)(j * 64) * K, &Bs[c ^ 1][(j * 64 + wave * 8) * 64]);
      asm volatile("s_waitcnt vmcnt(6)" ::: "memory");  // tile t landed; t+1 in flight
    } else {
      asm volatile("s_waitcnt vmcnt(0)" ::: "memory");
    }
    __builtin_amdgcn_sched_barrier(0);
    __builtin_amdgcn_s_barrier();   // all waves' tile-t data visible
    __builtin_amdgcn_sched_barrier(0);

    bf8v b[4][2];
#pragma unroll
    for (int fn = 0; fn < 4; ++fn) {
      b[fn][0] = *(const bf8v*)&Bs[c][(rB + fn * 16 + lo) * 64 + csw0];
      b[fn][1] = *(const bf8v*)&Bs[c][(rB + fn * 16 + lo) * 64 + csw1];
    }
#pragma unroll
    for (int p = 0; p < 2; ++p) {
      bf8v a[2][2];
#pragma unroll
      for (int i = 0; i < 2; ++i) {
        a[i][0] = *(const bf8v*)&As[c][(rA + (p * 2 + i) * 16 + lo) * 64 + csw0];
        a[i][1] = *(const bf8v*)&As[c][(rA + (p * 2 + i) * 16 + lo) * 64 + csw1];
      }
      __builtin_amdgcn_s_setprio(1);
#pragma unroll
      for (int ks = 0; ks < 2; ++ks)
#pragma unroll
        for (int i = 0; i < 2; ++i)
#pragma unroll
          for (int fn = 0; fn < 4; ++fn)
            acc[p * 2 + i][fn] = __builtin_amdgcn_mfma_f32_16x16x32_bf16(
                a[i][ks], b[fn][ks], acc[p * 2 + i][fn], 0, 0, 0);
      __builtin_amdgcn_s_setprio(0);
    }
  }

  // epilogue
#pragma unroll
  for (int i = 0; i < 4; ++i) {
#pragma unroll
    for (int j = 0; j < 4; ++j) {
      const int col = n0 + wn * 64 + j * 16 + lo;
      const int row0 = m0 + wm * 64 + i * 16 + hi * 4;
      if (MODE == 0) {
        float* C = (float*)Cv;
#pragma unroll
        for (int r = 0; r < 4; ++r)
          C[(size_t)(row0 + r) * N + col] = acc[i][j][r] + bias[col];
      } else {
        unsigned short* C = (unsigned short*)Cv;
        const float bb = bias[col];
        if (col < 2048) {
          const float sc = (col < 1024) ? scale : 1.0f;
#pragma unroll
          for (int r = 0; r < 4; ++r)
            C[(size_t)(row0 + r) * 2048 + col] = f2bf((acc[i][j][r] + bb) * sc);
        } else {
          // V column -> vtg[b][h][d][token], 4 consecutive tokens per lane
          const int d = (col - 2048) & 63, hh = (col - 2048) >> 6;
          const int bbt = row0 >> 11, tok = row0 & 2047;
          ushort4 o;
          o.x = f2bf(acc[i][j][0] + bb);
          o.y = f2bf(acc[i][j][1] + bb);
          o.z = f2bf(acc[i][j][2] + bb);
          o.w = f2bf(acc[i][j][3] + bb);
          *(ushort4*)&vtg[((((size_t)bbt * 16 + hh) * 64 + d) * 2048) + tok] = o;
        }
      }
    }
  }
}

// ---------------- flash attention v7 (round-5 verified structure; QK stride 2048) ----------------
// Double-buffered Kt/Vt, ONE barrier per kt. Race ledger: buf[c^1] overwrite at kt
// is safe (readers done before barrier kt-1); buf[c] reads see kt-1 writes
// (lgkm(0)+barrier). All barriers wave-uniform. LDS 73.7 KiB -> 2 blocks/CU.
#define FSTR 72   // LDS row stride (shorts): 64 payload + 8 pad

__global__ __launch_bounds__(256, 2) void flash_attn(
    const unsigned short* __restrict__ qk,    // [8192][2048]: Q cols 0..1023, K cols 1024..2047
    const unsigned short* __restrict__ vtg,   // [b*16+h][64][2048]
    unsigned short* __restrict__ y) {
  __shared__ __align__(16) unsigned short Ps[256 * FSTR];   // Q stage, then P tile [q][key]
  __shared__ __align__(16) unsigned short Kt[2][64 * FSTR]; // K tiles [key][d], dbuf
  __shared__ __align__(16) unsigned short Vt[2][64 * FSTR]; // V^T tiles [d][key], dbuf
  const int tid = threadIdx.x;
  const int wave = tid >> 6, lane = tid & 63;
  const int lo = lane & 15, hi = lane >> 4;

  // XCD swizzle: 512 blocks; XCD c gets one b, 8 heads (~3MB QK/V -> L2-resident)
  const int lin = blockIdx.x;
  const int swz = (lin & 7) * 64 + (lin >> 3);
  const int q0 = (swz & 7) << 8;        // 8 q-blocks of 256
  const int h  = (swz >> 3) & 15;
  const int b  = swz >> 7;

  const size_t base = (size_t)b * 2048 * 2048;
  const int qoff = h * 64, koff = 1024 + h * 64;
  const unsigned short* vsrc = vtg + (size_t)(b * 16 + h) * 64 * 2048;

  // ---- K/V staging: reg-held prefetch
  const int m_st = tid >> 3, c_st = tid & 7;
  const unsigned short* kg = qk + base + koff;
  float4 rk0, rk1, rv0, rv1;
  auto kv_load = [&](int kt) {
    const int mb = kt * 64;
    rk0 = *(const float4*)(kg + (size_t)(mb + m_st) * 2048 + c_st * 8);
    rk1 = *(const float4*)(kg + (size_t)(mb + m_st + 32) * 2048 + c_st * 8);
    rv0 = *(const float4*)(vsrc + (size_t)m_st * 2048 + mb + c_st * 8);
    rv1 = *(const float4*)(vsrc + (size_t)(m_st + 32) * 2048 + mb + c_st * 8);
  };
  auto kv_write = [&](int buf) {
    *(float4*)&Kt[buf][m_st * FSTR + c_st * 8] = rk0;
    *(float4*)&Kt[buf][(m_st + 32) * FSTR + c_st * 8] = rk1;
    *(float4*)&Vt[buf][m_st * FSTR + c_st * 8] = rv0;
    *(float4*)&Vt[buf][(m_st + 32) * FSTR + c_st * 8] = rv1;
  };

  kv_load(0);

  // ---- stage Q~ into Ps region [256][FSTR]
#pragma unroll
  for (int i = 0; i < 8; ++i) {
    int cid = i * 256 + tid;
    int m = cid >> 3, c = cid & 7;
    *(float4*)&Ps[m * FSTR + c * 8] =
        *(const float4*)(qk + base + (size_t)(q0 + m) * 2048 + qoff + c * 8);
  }
  __syncthreads();
  // preload Q^T B-operand frags (wave-local rows; later P-writes are in-wave ordered)
  bf8v bq[4][2];  // [qt][ks]
#pragma unroll
  for (int qt = 0; qt < 4; ++qt)
#pragma unroll
    for (int ks = 0; ks < 2; ++ks)
      bq[qt][ks] = *(const bf8v*)&Ps[(wave * 64 + qt * 16 + lo) * FSTR + ks * 32 + hi * 8];

  f4v O[4][4] = {};       // [qt][dt]
  f4v acc_l[4] = {};      // row-sums via MFMA x ones (same C/D layout as O)
  union { bf8v v; unsigned short u[8]; } onesu;
#pragma unroll
  for (int i = 0; i < 8; ++i) onesu.u[i] = 0x3F80;  // bf16 1.0
  const bf8v ones = onesu.v;

  // prologue: buf0 <- tile 0; issue tile-1 loads; certify buf0
  kv_write(0);
  kv_load(1);
  asm volatile("s_waitcnt lgkmcnt(0)" ::: "memory");
  __builtin_amdgcn_s_barrier();
  asm volatile("" ::: "memory");

  for (int kt = 0; kt < 32; ++kt) {
    const int c = kt & 1;
    // stage next tile into the other buffer (readers of it finished at barrier(kt-1))
    if (kt < 31) {
      kv_write(c ^ 1);              // regs from kv_load(kt+1)
      if (kt < 30) kv_load(kt + 2); // issue; stays in flight across barriers
    }

    // ---- S^T = K . Q~^T, ct-outer: one 16-key strip at a time
#pragma unroll
    for (int ct = 0; ct < 4; ++ct) {
      f4v s[4] = {{}, {}, {}, {}};
      __builtin_amdgcn_s_setprio(1);
#pragma unroll
      for (int ks = 0; ks < 2; ++ks) {
        bf8v ak = *(const bf8v*)&Kt[c][(ct * 16 + lo) * FSTR + ks * 32 + hi * 8];
#pragma unroll
        for (int qt = 0; qt < 4; ++qt)
          s[qt] = __builtin_amdgcn_mfma_f32_16x16x32_bf16(ak, bq[qt][ks], s[qt], 0, 0, 0);
      }
      __builtin_amdgcn_s_setprio(0);
#pragma unroll
      for (int qt = 0; qt < 4; ++qt) {
        float p0 = exp2_hw(s[qt][0]), p1 = exp2_hw(s[qt][1]);
        float p2 = exp2_hw(s[qt][2]), p3 = exp2_hw(s[qt][3]);
        uint2 w; w.x = pk2bf(p0, p1); w.y = pk2bf(p2, p3);
        *(uint2*)&Ps[(wave * 64 + qt * 16 + lo) * FSTR + ct * 16 + hi * 4] = w;
      }
    }

    // ---- O += P.V ; l += P.1
#pragma unroll
    for (int ks = 0; ks < 2; ++ks) {
      bf8v ap[4];
#pragma unroll
      for (int qt = 0; qt < 4; ++qt)
        ap[qt] = *(const bf8v*)&Ps[(wave * 64 + qt * 16 + lo) * FSTR + ks * 32 + hi * 8];
      __builtin_amdgcn_s_setprio(1);
#pragma unroll
      for (int qt = 0; qt < 4; ++qt)
        acc_l[qt] = __builtin_amdgcn_mfma_f32_16x16x32_bf16(ap[qt], ones, acc_l[qt], 0, 0, 0);
#pragma unroll
      for (int dt = 0; dt < 4; ++dt) {
        bf8v bv = *(const bf8v*)&Vt[c][(dt * 16 + lo) * FSTR + ks * 32 + hi * 8];
#pragma unroll
        for (int qt = 0; qt < 4; ++qt)
          O[qt][dt] = __builtin_amdgcn_mfma_f32_16x16x32_bf16(ap[qt], bv, O[qt][dt], 0, 0, 0);
      }
      __builtin_amdgcn_s_setprio(0);
    }

    asm volatile("s_waitcnt lgkmcnt(0)" ::: "memory");
    __builtin_amdgcn_s_barrier();   // single barrier per kt
    asm volatile("" ::: "memory");
  }

  // epilogue: acc_l matches O's C/D layout -> no cross-lane reduction
#pragma unroll
  for (int qt = 0; qt < 4; ++qt) {
#pragma unroll
    for (int r = 0; r < 4; ++r) {
      float inv = 1.f / acc_l[qt][r];
      int row = q0 + wave * 64 + qt * 16 + hi * 4 + r;
      size_t orow = ((size_t)b * 2048 + row) * 1024 + h * 64;
#pragma unroll
      for (int dt = 0; dt < 4; ++dt)
        y[orow + dt * 16 + lo] = f2bf(O[qt][dt][r] * inv);
    }
  }
}

// ---------------- launch ----------------
extern "C" void kernel_launch(void* const* d_in, const int* in_sizes, int n_in,
                              void* d_out, int out_size, void* d_ws, size_t ws_size,
                              hipStream_t stream) {
  (void)in_sizes; (void)n_in; (void)out_size; (void)ws_size;
  const float* x     = (const float*)d_in[0];
  const float* w_in  = (const float*)d_in[1];
  const float* b_in  = (const float*)d_in[2];
  const float* w_out = (const float*)d_in[3];
  const float* b_out = (const float*)d_in[4];

  // workspace layout (bf16 elements), 88 MB total — same footprint as before:
  // qkv is split into QK (8192x2048) + vtg (V^T, written directly by gemm1).
  unsigned short* xb  = (unsigned short*)d_ws;          // 8192x1024
  unsigned short* wiT = xb  + (size_t)8192 * 1024;      // 3072x1024 (w_in^T)
  unsigned short* woT = wiT + (size_t)3072 * 1024;      // 1024x1024 (w_out^T)
  unsigned short* qk  = woT + (size_t)1024 * 1024;      // 8192x2048 (Q|K)
  unsigned short* vtg = qk  + (size_t)8192 * 2048;      // 64x64x2048 (V^T)
  unsigned short* yb  = vtg + (size_t)64 * 64 * 2048;   // 8192x1024

  // cast + weight transpose fused (one launch)
  prep_kernel<<<12288, 256, 0, stream>>>(x, w_in, w_out, xb, wiT, woT);

  // qkv GEMM: Q,K -> qk (Q scaled by log2e); V -> vtg transposed (no transpose_v kernel)
  gemm256<1><<<768, 512, 0, stream>>>(xb, wiT, b_in, qk, vtg, 3072, 1024, 24, L2E);
  // attention -> yb
  flash_attn<<<512, 256, 0, stream>>>(qk, vtg, yb);
  // out = yb @ w_out + b_out; 256x128 tiles: grid 32x8 = 256 blocks = 1 round
  gemm256<0><<<256, 512, 0, stream>>>(yb, woT, b_out, d_out, nullptr, 1024, 1024, 8, 1.0f);
}

// Round 8
// 272.845 us; speedup vs baseline: 1.1832x; 1.0072x over previous
//
#include <hip/hip_runtime.h>
#include <hip/hip_bf16.h>
#include <stdint.h>

typedef __attribute__((ext_vector_type(8))) __bf16 bf8v;   // MFMA A/B frag: 8 bf16 = 4 VGPR
typedef __attribute__((ext_vector_type(4))) float f4v;     // MFMA C/D frag

#define L2E 1.44269504088896f

// fp32 -> bf16 round-to-nearest-even (bit pattern as ushort)
__device__ __forceinline__ unsigned short f2bf(float f) {
  union { float f; unsigned u; } v; v.f = f;
  unsigned r = v.u + 0x7fffu + ((v.u >> 16) & 1u);
  return (unsigned short)(r >> 16);
}

// pack two fp32 -> dword of two RNE bf16 (low = f0), HW v_cvt_pk_bf16_f32 path
__device__ __forceinline__ unsigned pk2bf(float f0, float f1) {
  union { __hip_bfloat162 h; unsigned u; } c;
  c.h = __float22bfloat162_rn(make_float2(f0, f1));
  return c.u;
}

// 2^x via v_exp_f32
__device__ __forceinline__ float exp2_hw(float x) {
  return __builtin_amdgcn_exp2f(x);
}

// async global->LDS, 16B per lane; LDS dest = wave-uniform base + lane*16
__device__ __forceinline__ void gl_lds16(const void* g, void* l) {
  __builtin_amdgcn_global_load_lds(
      (__attribute__((address_space(1))) void*)(g),
      (__attribute__((address_space(3))) void*)(l), 16, 0, 0);
}

// ---------------- fused prep: cast x -> bf16  +  weight transpose/cast ----------------
__global__ void prep_kernel(const float* __restrict__ x,
                            const float* __restrict__ w_in,
                            const float* __restrict__ w_out,
                            unsigned short* __restrict__ xb,
                            unsigned short* __restrict__ wiT,
                            unsigned short* __restrict__ woT) {
  __shared__ float tile[32][33];
  int bx = blockIdx.x;
  if (bx < 8192) {
    int i = bx * 256 + threadIdx.x;
    float4 v = ((const float4*)x)[i];
    ushort4 o;
    o.x = f2bf(v.x); o.y = f2bf(v.y); o.z = f2bf(v.z); o.w = f2bf(v.w);
    ((ushort4*)xb)[i] = o;
    return;
  }
  int idx = bx - 8192;              // 0..4095 -> (128 x, 32 y)
  int bxx = idx & 127, byy = idx >> 7;
  const float* in; unsigned short* out; int C, c0;
  if (bxx < 96) { in = w_in;  out = wiT; C = 3072; c0 = bxx * 32; }
  else          { in = w_out; out = woT; C = 1024; c0 = (bxx - 96) * 32; }
  int r0 = byy * 32;
  int tx = threadIdx.x & 31, ty = threadIdx.x >> 5;
#pragma unroll
  for (int j = 0; j < 4; ++j)
    tile[ty + 8 * j][tx] = in[(size_t)(r0 + ty + 8 * j) * C + c0 + tx];
  __syncthreads();
#pragma unroll
  for (int j = 0; j < 4; ++j)
    out[(size_t)(c0 + ty + 8 * j) * 1024 + r0 + tx] = f2bf(tile[tx][ty + 8 * j]);
}

// ---------------- GEMM1: 256x256, BK=64, 8-PHASE deep pipeline (m201-template port) ----------------
// 8 waves (2M x 4N), per-wave 128x64 = acc[8][4]. LDS 128 KiB (A/B double-buffered
// 256x64 K-tiles). Per K-tile: 4 phases of {ds-reads, stage 1 half-tile, barrier,
// 16 MFMA (setprio), barrier}. Staging ledger (no latency assumptions):
//  - G_t phases 0,1 stage A(t+1) -> buf c^1  (disjoint from buf c being read: safe)
//  - G_t phases 2,3 stage B(t+2) -> buf c B-region (dead after phase 0's reads,
//    ordered by the phase-0 trailing barrier: safe)
//  - group-end vmcnt(4): certifies tile t+1 fully landed (only B(t+2)=4 loads newer).
// Outputs: Q cols (<1024, scaled) and K cols -> qk[row*2048+col]; V cols (>=2048)
// -> vtg[b][h][d][token] transposed.
__global__ __launch_bounds__(512, 2) void gemm1_8ph(
    const unsigned short* __restrict__ A,
    const unsigned short* __restrict__ BT,
    const float* __restrict__ bias,
    unsigned short* __restrict__ qk,
    unsigned short* __restrict__ vtg,
    int K, int nbx, float scale) {
  __shared__ __align__(16) unsigned short As[2][256 * 64];
  __shared__ __align__(16) unsigned short Bs[2][256 * 64];
  const int tid = threadIdx.x;
  const int wave = tid >> 6, lane = tid & 63;
  const int lo = lane & 15, hi = lane >> 4;
  const int wm = wave >> 2, wn = wave & 3;   // 2M x 4N

  // XCD-aware swizzle (grid %8 == 0)
  const int cpx = gridDim.x >> 3;
  const int s = (blockIdx.x & 7) * cpx + (blockIdx.x >> 3);
  const int by = s / nbx, bx = s - by * nbx;
  const int m0 = by * 256, n0 = bx * 256;

  // staging: per gl_lds call 512 threads cover 64 rows x 64 k; 3-bit chunk swizzle
  // (c8 ^= row&7) pre-applied on the global source (linear LDS dest).
  const int srow = lane >> 3;
  const int scol = (((lane & 7) ^ (srow & 7)) * 8);
  const unsigned short* gA = A + (size_t)(m0 + wave * 8 + srow) * K + scol;
  const unsigned short* gB = BT + (size_t)(n0 + wave * 8 + srow) * K + scol;

  // ds_read cols (shorts): chunk (ks*4+hi) ^ (row&7), row&7 == lo&7
  const int csw0 = ((hi ^ (lo & 7)) * 8);
  const int csw1 = (((4 + hi) ^ (lo & 7)) * 8);
  const int rA = wm * 128;   // + frag*16 + lo
  const int rB = wn * 64;    // + fn*16 + lo

  f4v acc[8][4] = {};
  const int nt = K >> 6;

  // stage half `half` (128 rows) of K-tile t into buffer `buf` (2 gl_lds calls)
  auto stageA = [&](int t, int buf, int half) {
    const unsigned short* g = gA + (size_t)(half * 128) * K + t * 64;
#pragma unroll
    for (int j = 0; j < 2; ++j)
      gl_lds16(g + (size_t)(j * 64) * K, &As[buf][(half * 128 + j * 64 + wave * 8) * 64]);
  };
  auto stageB = [&](int t, int buf, int half) {
    const unsigned short* g = gB + (size_t)(half * 128) * K + t * 64;
#pragma unroll
    for (int j = 0; j < 2; ++j)
      gl_lds16(g + (size_t)(j * 64) * K, &Bs[buf][(half * 128 + j * 64 + wave * 8) * 64]);
  };

  // prologue: tile0 complete (A+B) + B(tile1); vmcnt(4) certifies tile0.
  stageA(0, 0, 0); stageA(0, 0, 1);
  stageB(0, 0, 0); stageB(0, 0, 1);
  if (nt > 1) { stageB(1, 1, 0); stageB(1, 1, 1); }
  asm volatile("s_waitcnt vmcnt(4)" ::: "memory");
  __builtin_amdgcn_sched_barrier(0);
  __builtin_amdgcn_s_barrier();

  for (int t = 0; t < nt; ++t) {
    const int c = t & 1;
    bf8v b[4][2];
#pragma unroll
    for (int p = 0; p < 4; ++p) {
      // ---- phase-p ds reads (phase 0: all B + A frags 0,1; else 4 A frags)
      if (p == 0) {
#pragma unroll
        for (int fn = 0; fn < 4; ++fn) {
          b[fn][0] = *(const bf8v*)&Bs[c][(rB + fn * 16 + lo) * 64 + csw0];
          b[fn][1] = *(const bf8v*)&Bs[c][(rB + fn * 16 + lo) * 64 + csw1];
        }
      }
      bf8v a[2][2];
#pragma unroll
      for (int i = 0; i < 2; ++i) {
        a[i][0] = *(const bf8v*)&As[c][(rA + (p * 2 + i) * 16 + lo) * 64 + csw0];
        a[i][1] = *(const bf8v*)&As[c][(rA + (p * 2 + i) * 16 + lo) * 64 + csw1];
      }
      // ---- stage 1 half-tile (ledger above)
      if (p < 2) {
        if (t + 1 < nt) stageA(t + 1, c ^ 1, p);
      } else {
        if (t + 2 < nt) stageB(t + 2, c, p - 2);
      }
      // ---- group-end counted wait: certify tile t+1 before next group
      if (p == 3 && t + 1 < nt) {
        if (t + 2 < nt) asm volatile("s_waitcnt vmcnt(4)" ::: "memory");
        else            asm volatile("s_waitcnt vmcnt(0)" ::: "memory");
        __builtin_amdgcn_sched_barrier(0);
      }
      __builtin_amdgcn_s_barrier();
      // ---- 16 MFMA (compiler inserts fine-grained lgkmcnt before first use)
      __builtin_amdgcn_s_setprio(1);
#pragma unroll
      for (int ks = 0; ks < 2; ++ks)
#pragma unroll
        for (int i = 0; i < 2; ++i)
#pragma unroll
          for (int fn = 0; fn < 4; ++fn)
            acc[p * 2 + i][fn] = __builtin_amdgcn_mfma_f32_16x16x32_bf16(
                a[i][ks], b[fn][ks], acc[p * 2 + i][fn], 0, 0, 0);
      __builtin_amdgcn_s_setprio(0);
      __builtin_amdgcn_s_barrier();
    }
  }

  // epilogue: Q/K -> qk (stride 2048), V -> vtg transposed
#pragma unroll
  for (int i = 0; i < 8; ++i) {
#pragma unroll
    for (int j = 0; j < 4; ++j) {
      const int col = n0 + wn * 64 + j * 16 + lo;
      const int row0 = m0 + wm * 128 + i * 16 + hi * 4;
      const float bb = bias[col];
      if (col < 2048) {
        const float sc = (col < 1024) ? scale : 1.0f;
#pragma unroll
        for (int r = 0; r < 4; ++r)
          qk[(size_t)(row0 + r) * 2048 + col] = f2bf((acc[i][j][r] + bb) * sc);
      } else {
        const int d = (col - 2048) & 63, hh = (col - 2048) >> 6;
        const int bbt = row0 >> 11, tok = row0 & 2047;
        ushort4 o;
        o.x = f2bf(acc[i][j][0] + bb);
        o.y = f2bf(acc[i][j][1] + bb);
        o.z = f2bf(acc[i][j][2] + bb);
        o.w = f2bf(acc[i][j][3] + bb);
        *(ushort4*)&vtg[((((size_t)bbt * 16 + hh) * 64 + d) * 2048) + tok] = o;
      }
    }
  }
}

// ---------------- GEMM2: 256x128 tile, BK=64, 2-phase deep pipeline (round-5 verified) ----------------
__global__ __launch_bounds__(512, 2) void gemm2k(
    const unsigned short* __restrict__ A,
    const unsigned short* __restrict__ BT,
    const float* __restrict__ bias,
    float* __restrict__ C,
    int N, int K, int nbx) {
  __shared__ __align__(16) unsigned short As[2][256 * 64];
  __shared__ __align__(16) unsigned short Bs[2][128 * 64];
  const int tid = threadIdx.x;
  const int wave = tid >> 6, lane = tid & 63;
  const int lo = lane & 15, hi = lane >> 4;
  const int wm = wave >> 1, wn = wave & 1;

  const int cpx = gridDim.x >> 3;
  const int s = (blockIdx.x & 7) * cpx + (blockIdx.x >> 3);
  const int by = s / nbx, bx = s - by * nbx;
  const int m0 = by * 256, n0 = bx * 128;

  const int srow = lane >> 3;
  const int scol = (((lane & 7) ^ (srow & 7)) * 8);
  const unsigned short* gA = A + (size_t)(m0 + wave * 8 + srow) * K + scol;
  const unsigned short* gB = BT + (size_t)(n0 + wave * 8 + srow) * K + scol;

  const int csw0 = ((hi ^ (lo & 7)) * 8);
  const int csw1 = (((4 + hi) ^ (lo & 7)) * 8);
  const int rA = wm * 64;
  const int rB = wn * 64;

  f4v acc[4][4] = {};
  const int nt = K >> 6;

#pragma unroll
  for (int j = 0; j < 4; ++j)
    gl_lds16(gA + (size_t)(j * 64) * K, &As[0][(j * 64 + wave * 8) * 64]);
#pragma unroll
  for (int j = 0; j < 2; ++j)
    gl_lds16(gB + (size_t)(j * 64) * K, &Bs[0][(j * 64 + wave * 8) * 64]);

  for (int t = 0; t < nt; ++t) {
    const int c = t & 1;
    __builtin_amdgcn_s_barrier();
    __builtin_amdgcn_sched_barrier(0);
    if (t + 1 < nt) {
      const unsigned short* gA1 = gA + (size_t)(t + 1) * 64;
      const unsigned short* gB1 = gB + (size_t)(t + 1) * 64;
#pragma unroll
      for (int j = 0; j < 4; ++j)
        gl_lds16(gA1 + (size_t)(j * 64) * K, &As[c ^ 1][(j * 64 + wave * 8) * 64]);
#pragma unroll
      for (int j = 0; j < 2; ++j)
        gl_lds16(gB1 + (size_t)(j * 64) * K, &Bs[c ^ 1][(j * 64 + wave * 8) * 64]);
      asm volatile("s_waitcnt vmcnt(6)" ::: "memory");
    } else {
      asm volatile("s_waitcnt vmcnt(0)" ::: "memory");
    }
    __builtin_amdgcn_sched_barrier(0);
    __builtin_amdgcn_s_barrier();
    __builtin_amdgcn_sched_barrier(0);

    bf8v b[4][2];
#pragma unroll
    for (int fn = 0; fn < 4; ++fn) {
      b[fn][0] = *(const bf8v*)&Bs[c][(rB + fn * 16 + lo) * 64 + csw0];
      b[fn][1] = *(const bf8v*)&Bs[c][(rB + fn * 16 + lo) * 64 + csw1];
    }
#pragma unroll
    for (int p = 0; p < 2; ++p) {
      bf8v a[2][2];
#pragma unroll
      for (int i = 0; i < 2; ++i) {
        a[i][0] = *(const bf8v*)&As[c][(rA + (p * 2 + i) * 16 + lo) * 64 + csw0];
        a[i][1] = *(const bf8v*)&As[c][(rA + (p * 2 + i) * 16 + lo) * 64 + csw1];
      }
      __builtin_amdgcn_s_setprio(1);
#pragma unroll
      for (int ks = 0; ks < 2; ++ks)
#pragma unroll
        for (int i = 0; i < 2; ++i)
#pragma unroll
          for (int fn = 0; fn < 4; ++fn)
            acc[p * 2 + i][fn] = __builtin_amdgcn_mfma_f32_16x16x32_bf16(
                a[i][ks], b[fn][ks], acc[p * 2 + i][fn], 0, 0, 0);
      __builtin_amdgcn_s_setprio(0);
    }
  }

#pragma unroll
  for (int i = 0; i < 4; ++i) {
#pragma unroll
    for (int r = 0; r < 4; ++r) {
      int row = m0 + wm * 64 + i * 16 + hi * 4 + r;
#pragma unroll
      for (int j = 0; j < 4; ++j) {
        int col = n0 + wn * 64 + j * 16 + lo;
        C[(size_t)row * N + col] = acc[i][j][r] + bias[col];
      }
    }
  }
}

// ---------------- flash attention v7 (round-5/7 verified structure; QK stride 2048) ----------------
#define FSTR 72   // LDS row stride (shorts): 64 payload + 8 pad

__global__ __launch_bounds__(256, 2) void flash_attn(
    const unsigned short* __restrict__ qk,    // [8192][2048]: Q cols 0..1023, K cols 1024..2047
    const unsigned short* __restrict__ vtg,   // [b*16+h][64][2048]
    unsigned short* __restrict__ y) {
  __shared__ __align__(16) unsigned short Ps[256 * FSTR];   // Q stage, then P tile [q][key]
  __shared__ __align__(16) unsigned short Kt[2][64 * FSTR]; // K tiles [key][d], dbuf
  __shared__ __align__(16) unsigned short Vt[2][64 * FSTR]; // V^T tiles [d][key], dbuf
  const int tid = threadIdx.x;
  const int wave = tid >> 6, lane = tid & 63;
  const int lo = lane & 15, hi = lane >> 4;

  // XCD swizzle: 512 blocks; XCD c gets one b, 8 heads (~3MB QK/V -> L2-resident)
  const int lin = blockIdx.x;
  const int swz = (lin & 7) * 64 + (lin >> 3);
  const int q0 = (swz & 7) << 8;        // 8 q-blocks of 256
  const int h  = (swz >> 3) & 15;
  const int b  = swz >> 7;

  const size_t base = (size_t)b * 2048 * 2048;
  const int qoff = h * 64, koff = 1024 + h * 64;
  const unsigned short* vsrc = vtg + (size_t)(b * 16 + h) * 64 * 2048;

  // ---- K/V staging: reg-held prefetch
  const int m_st = tid >> 3, c_st = tid & 7;
  const unsigned short* kg = qk + base + koff;
  float4 rk0, rk1, rv0, rv1;
  auto kv_load = [&](int kt) {
    const int mb = kt * 64;
    rk0 = *(const float4*)(kg + (size_t)(mb + m_st) * 2048 + c_st * 8);
    rk1 = *(const float4*)(kg + (size_t)(mb + m_st + 32) * 2048 + c_st * 8);
    rv0 = *(const float4*)(vsrc + (size_t)m_st * 2048 + mb + c_st * 8);
    rv1 = *(const float4*)(vsrc + (size_t)(m_st + 32) * 2048 + mb + c_st * 8);
  };
  auto kv_write = [&](int buf) {
    *(float4*)&Kt[buf][m_st * FSTR + c_st * 8] = rk0;
    *(float4*)&Kt[buf][(m_st + 32) * FSTR + c_st * 8] = rk1;
    *(float4*)&Vt[buf][m_st * FSTR + c_st * 8] = rv0;
    *(float4*)&Vt[buf][(m_st + 32) * FSTR + c_st * 8] = rv1;
  };

  kv_load(0);

  // ---- stage Q~ into Ps region [256][FSTR]
#pragma unroll
  for (int i = 0; i < 8; ++i) {
    int cid = i * 256 + tid;
    int m = cid >> 3, c = cid & 7;
    *(float4*)&Ps[m * FSTR + c * 8] =
        *(const float4*)(qk + base + (size_t)(q0 + m) * 2048 + qoff + c * 8);
  }
  __syncthreads();
  // preload Q^T B-operand frags (wave-local rows; later P-writes are in-wave ordered)
  bf8v bq[4][2];  // [qt][ks]
#pragma unroll
  for (int qt = 0; qt < 4; ++qt)
#pragma unroll
    for (int ks = 0; ks < 2; ++ks)
      bq[qt][ks] = *(const bf8v*)&Ps[(wave * 64 + qt * 16 + lo) * FSTR + ks * 32 + hi * 8];

  f4v O[4][4] = {};       // [qt][dt]
  f4v acc_l[4] = {};      // row-sums via MFMA x ones (same C/D layout as O)
  union { bf8v v; unsigned short u[8]; } onesu;
#pragma unroll
  for (int i = 0; i < 8; ++i) onesu.u[i] = 0x3F80;  // bf16 1.0
  const bf8v ones = onesu.v;

  // prologue: buf0 <- tile 0; issue tile-1 loads; certify buf0
  kv_write(0);
  kv_load(1);
  asm volatile("s_waitcnt lgkmcnt(0)" ::: "memory");
  __builtin_amdgcn_s_barrier();
  asm volatile("" ::: "memory");

  for (int kt = 0; kt < 32; ++kt) {
    const int c = kt & 1;
    if (kt < 31) {
      kv_write(c ^ 1);              // regs from kv_load(kt+1)
      if (kt < 30) kv_load(kt + 2); // issue; stays in flight across barriers
    }

    // ---- S^T = K . Q~^T, ct-outer: one 16-key strip at a time
#pragma unroll
    for (int ct = 0; ct < 4; ++ct) {
      f4v s[4] = {{}, {}, {}, {}};
      __builtin_amdgcn_s_setprio(1);
#pragma unroll
      for (int ks = 0; ks < 2; ++ks) {
        bf8v ak = *(const bf8v*)&Kt[c][(ct * 16 + lo) * FSTR + ks * 32 + hi * 8];
#pragma unroll
        for (int qt = 0; qt < 4; ++qt)
          s[qt] = __builtin_amdgcn_mfma_f32_16x16x32_bf16(ak, bq[qt][ks], s[qt], 0, 0, 0);
      }
      __builtin_amdgcn_s_setprio(0);
#pragma unroll
      for (int qt = 0; qt < 4; ++qt) {
        float p0 = exp2_hw(s[qt][0]), p1 = exp2_hw(s[qt][1]);
        float p2 = exp2_hw(s[qt][2]), p3 = exp2_hw(s[qt][3]);
        uint2 w; w.x = pk2bf(p0, p1); w.y = pk2bf(p2, p3);
        *(uint2*)&Ps[(wave * 64 + qt * 16 + lo) * FSTR + ct * 16 + hi * 4] = w;
      }
    }

    // ---- O += P.V ; l += P.1
#pragma unroll
    for (int ks = 0; ks < 2; ++ks) {
      bf8v ap[4];
#pragma unroll
      for (int qt = 0; qt < 4; ++qt)
        ap[qt] = *(const bf8v*)&Ps[(wave * 64 + qt * 16 + lo) * FSTR + ks * 32 + hi * 8];
      __builtin_amdgcn_s_setprio(1);
#pragma unroll
      for (int qt = 0; qt < 4; ++qt)
        acc_l[qt] = __builtin_amdgcn_mfma_f32_16x16x32_bf16(ap[qt], ones, acc_l[qt], 0, 0, 0);
#pragma unroll
      for (int dt = 0; dt < 4; ++dt) {
        bf8v bv = *(const bf8v*)&Vt[c][(dt * 16 + lo) * FSTR + ks * 32 + hi * 8];
#pragma unroll
        for (int qt = 0; qt < 4; ++qt)
          O[qt][dt] = __builtin_amdgcn_mfma_f32_16x16x32_bf16(ap[qt], bv, O[qt][dt], 0, 0, 0);
      }
      __builtin_amdgcn_s_setprio(0);
    }

    asm volatile("s_waitcnt lgkmcnt(0)" ::: "memory");
    __builtin_amdgcn_s_barrier();   // single barrier per kt
    asm volatile("" ::: "memory");
  }

  // epilogue: acc_l matches O's C/D layout -> no cross-lane reduction
#pragma unroll
  for (int qt = 0; qt < 4; ++qt) {
#pragma unroll
    for (int r = 0; r < 4; ++r) {
      float inv = 1.f / acc_l[qt][r];
      int row = q0 + wave * 64 + qt * 16 + hi * 4 + r;
      size_t orow = ((size_t)b * 2048 + row) * 1024 + h * 64;
#pragma unroll
      for (int dt = 0; dt < 4; ++dt)
        y[orow + dt * 16 + lo] = f2bf(O[qt][dt][r] * inv);
    }
  }
}

// ---------------- launch ----------------
extern "C" void kernel_launch(void* const* d_in, const int* in_sizes, int n_in,
                              void* d_out, int out_size, void* d_ws, size_t ws_size,
                              hipStream_t stream) {
  (void)in_sizes; (void)n_in; (void)out_size; (void)ws_size;
  const float* x     = (const float*)d_in[0];
  const float* w_in  = (const float*)d_in[1];
  const float* b_in  = (const float*)d_in[2];
  const float* w_out = (const float*)d_in[3];
  const float* b_out = (const float*)d_in[4];

  // workspace layout (bf16 elements): qkv split into QK (8192x2048) + vtg
  unsigned short* xb  = (unsigned short*)d_ws;          // 8192x1024
  unsigned short* wiT = xb  + (size_t)8192 * 1024;      // 3072x1024 (w_in^T)
  unsigned short* woT = wiT + (size_t)3072 * 1024;      // 1024x1024 (w_out^T)
  unsigned short* qk  = woT + (size_t)1024 * 1024;      // 8192x2048 (Q|K)
  unsigned short* vtg = qk  + (size_t)8192 * 2048;      // 64x64x2048 (V^T)
  unsigned short* yb  = vtg + (size_t)64 * 64 * 2048;   // 8192x1024

  // cast + weight transpose fused (one launch)
  prep_kernel<<<12288, 256, 0, stream>>>(x, w_in, w_out, xb, wiT, woT);

  // qkv GEMM, 8-phase 256x256: Q,K -> qk (Q scaled by log2e); V -> vtg transposed
  // grid 32x12 = 384 blocks (%8==0 for XCD swizzle)
  gemm1_8ph<<<384, 512, 0, stream>>>(xb, wiT, b_in, qk, vtg, 1024, 12, L2E);
  // attention -> yb
  flash_attn<<<512, 256, 0, stream>>>(qk, vtg, yb);
  // out = yb @ w_out + b_out; 256x128 tiles: grid 32x8 = 256 blocks = 1 round
  gemm2k<<<256, 512, 0, stream>>>(yb, woT, b_out, (float*)d_out, 1024, 1024, 8);
}